// Round 1
// baseline (1433.660 us; speedup 1.0000x reference)
//
#include <hip/hip_runtime.h>
#include <hip/hip_bf16.h>
#include <math.h>

// Problem constants
#define B_SZ   2
#define LSEQ   1024
#define DMODEL 1024
#define DSTATE 16
#define DCONV  4
#define DINNER 2048
#define MROWS  (B_SZ * LSEQ)        // 2048

// ---------------- fp32 tiled GEMM: C[m,n] = sum_k A[m,k] * Bt[n,k] ----------
// BM=BN=64, BK=16, 256 threads, 4x4 micro-tile per thread.
// EPI: 0 = none, 1 = softplus(x + bias[n])
template<int EPI>
__global__ __launch_bounds__(256)
void gemm_nt(const float* __restrict__ A, int lda,
             const float* __restrict__ Bt, int ldb,
             const float* __restrict__ bias,
             float* __restrict__ C, int ldc,
             int M, int N, int K)
{
    __shared__ float As[16][68];
    __shared__ float Bs[16][68];
    const int tid = threadIdx.x;
    const int m0 = blockIdx.x * 64;
    const int n0 = blockIdx.y * 64;
    const int tm = tid & 15;        // micro-tile row group
    const int tn = tid >> 4;        // micro-tile col group
    const int lc = tid & 3;         // loader: k-chunk (4 floats)
    const int lr = tid >> 2;        // loader: row 0..63

    float acc[4][4] = {};

    for (int k0 = 0; k0 < K; k0 += 16) {
        float4 av = *(const float4*)&A [(size_t)(m0 + lr) * lda + k0 + 4 * lc];
        float4 bv = *(const float4*)&Bt[(size_t)(n0 + lr) * ldb + k0 + 4 * lc];
        As[4*lc+0][lr] = av.x; As[4*lc+1][lr] = av.y;
        As[4*lc+2][lr] = av.z; As[4*lc+3][lr] = av.w;
        Bs[4*lc+0][lr] = bv.x; Bs[4*lc+1][lr] = bv.y;
        Bs[4*lc+2][lr] = bv.z; Bs[4*lc+3][lr] = bv.w;
        __syncthreads();
        #pragma unroll
        for (int k = 0; k < 16; ++k) {
            float a[4], b[4];
            #pragma unroll
            for (int i = 0; i < 4; ++i) a[i] = As[k][tm*4 + i];
            #pragma unroll
            for (int j = 0; j < 4; ++j) b[j] = Bs[k][tn*4 + j];
            #pragma unroll
            for (int i = 0; i < 4; ++i)
                #pragma unroll
                for (int j = 0; j < 4; ++j)
                    acc[i][j] += a[i] * b[j];
        }
        __syncthreads();
    }

    #pragma unroll
    for (int i = 0; i < 4; ++i) {
        const int m = m0 + tm*4 + i;
        #pragma unroll
        for (int j = 0; j < 4; ++j) {
            const int n = n0 + tn*4 + j;
            float v = acc[i][j];
            if (EPI == 1) {
                v += bias[n];
                v = (v > 20.f) ? v : log1pf(__expf(v));
            }
            C[(size_t)m * ldc + n] = v;
        }
    }
}

// --------------- causal depthwise conv (k=4, left pad 3) + SiLU -------------
// xi = xz[:, 0:2048];  u[m,d] = silu(sum_j xi[b, t-3+j, d]*cw[d,j] + cb[d])
__global__ __launch_bounds__(256)
void conv_silu(const float* __restrict__ xz, const float* __restrict__ cw,
               const float* __restrict__ cb, float* __restrict__ u)
{
    int idx = blockIdx.x * blockDim.x + threadIdx.x;   // over MROWS*DINNER
    int d = idx & (DINNER - 1);
    int m = idx >> 11;                                  // DINNER = 2048
    int t = m & (LSEQ - 1);
    float acc = cb[d];
    #pragma unroll
    for (int j = 0; j < DCONV; ++j) {
        int tt = t - (DCONV - 1) + j;
        if (tt >= 0)
            acc += xz[(size_t)(m - t + tt) * 4096 + d] * cw[d * DCONV + j];
    }
    u[(size_t)m * DINNER + d] = acc / (1.f + __expf(-acc));
}

// -------------------- B/C projection: bc[m, 0:32] = u[m,:] @ Wx.T -----------
__global__ __launch_bounds__(64)
void bc_gemm(const float* __restrict__ u, const float* __restrict__ Wx,
             float* __restrict__ bc)
{
    int m = blockIdx.x;
    int lane = threadIdx.x;
    int n = lane & 31, half = lane >> 5;
    const float* ur = u  + (size_t)m * DINNER + half * (DINNER / 2);
    const float* wr = Wx + (size_t)n * DINNER + half * (DINNER / 2);
    float acc = 0.f;
    for (int k = 0; k < DINNER / 2; k += 4) {
        float4 uv = *(const float4*)&ur[k];
        float4 wv = *(const float4*)&wr[k];
        acc += uv.x*wv.x + uv.y*wv.y + uv.z*wv.z + uv.w*wv.w;
    }
    acc += __shfl_xor(acc, 32);
    if (half == 0) bc[m * 32 + n] = acc;
}

// ----------------------------- selective scan -------------------------------
// thread = (b, d, n); 16 d x 16 n per block. Fuses +D*u and *silu(z).
// Writes gated y into the (dead) xi half of xz: yg[m*4096 + d].
__global__ __launch_bounds__(256)
void scan_kernel(const float* __restrict__ dt, const float* __restrict__ u,
                 const float* __restrict__ bc, float* __restrict__ xz,
                 const float* __restrict__ A_log, const float* __restrict__ Dp)
{
    const int b  = blockIdx.y;
    const int d  = blockIdx.x * 16 + (threadIdx.x >> 4);
    const int n  = threadIdx.x & 15;
    const float Adn = -__expf(A_log[d * DSTATE + n]);
    const float Dd  = Dp[d];
    const float* dtb = dt + (size_t)b * LSEQ * DINNER;
    const float* ub  = u  + (size_t)b * LSEQ * DINNER;
    const float* bcb = bc + (size_t)b * LSEQ * 32;
    float* xzb = xz + (size_t)b * LSEQ * 4096;

    float s = 0.f;
    for (int t = 0; t < LSEQ; ++t) {
        float dtv = dtb[(size_t)t * DINNER + d];
        float uv  = ub [(size_t)t * DINNER + d];
        float Bv  = bcb[t * 32 + n];
        float Cv  = bcb[t * 32 + 16 + n];
        float a = __expf(dtv * Adn);
        s = a * s + dtv * Bv * uv;
        float p = s * Cv;
        p += __shfl_xor(p, 1, 16);
        p += __shfl_xor(p, 2, 16);
        p += __shfl_xor(p, 4, 16);
        p += __shfl_xor(p, 8, 16);
        if (n == 0) {
            float y  = p + Dd * uv;
            float zv = xzb[(size_t)t * 4096 + 2048 + d];
            xzb[(size_t)t * 4096 + d] = y * (zv / (1.f + __expf(-zv)));
        }
    }
}

// ---------------------------------------------------------------------------
extern "C" void kernel_launch(void* const* d_in, const int* in_sizes, int n_in,
                              void* d_out, int out_size, void* d_ws, size_t ws_size,
                              hipStream_t stream)
{
    const float* x      = (const float*)d_in[0];
    const float* W_in   = (const float*)d_in[1];
    const float* conv_w = (const float*)d_in[2];
    const float* conv_b = (const float*)d_in[3];
    const float* W_x    = (const float*)d_in[4];
    const float* W_dt   = (const float*)d_in[5];
    const float* b_dt   = (const float*)d_in[6];
    const float* A_log  = (const float*)d_in[7];
    const float* Dp     = (const float*)d_in[8];
    const float* W_out  = (const float*)d_in[9];
    float* out = (float*)d_out;

    float* ws = (float*)d_ws;
    float* xz = ws;                                   // 2048 x 4096
    float* u  = xz + (size_t)MROWS * 4096;            // 2048 x 2048
    float* dt = u  + (size_t)MROWS * DINNER;          // 2048 x 2048
    float* bc = dt + (size_t)MROWS * DINNER;          // 2048 x 32

    // 1. xz = x @ W_in.T           (M=2048, N=4096, K=1024)
    gemm_nt<0><<<dim3(32, 64), 256, 0, stream>>>(x, DMODEL, W_in, DMODEL,
                                                 nullptr, xz, 4096,
                                                 MROWS, 4096, DMODEL);
    // 2. u = silu(causal_conv(xi) + conv_b)
    conv_silu<<<(MROWS * DINNER) / 256, 256, 0, stream>>>(xz, conv_w, conv_b, u);
    // 3. dt = softplus(u @ W_dt.T + b_dt)   (M=2048, N=2048, K=2048)
    gemm_nt<1><<<dim3(32, 32), 256, 0, stream>>>(u, DINNER, W_dt, DINNER,
                                                 b_dt, dt, DINNER,
                                                 MROWS, DINNER, DINNER);
    // 4. bc = u @ W_x.T  (B then C, 16+16 per row)
    bc_gemm<<<MROWS, 64, 0, stream>>>(u, W_x, bc);
    // 5. scan + gate; writes y into xi half of xz
    scan_kernel<<<dim3(DINNER / 16, B_SZ), 256, 0, stream>>>(dt, u, bc, xz,
                                                             A_log, Dp);
    // 6. out = y @ W_out.T         (M=2048, N=1024, K=2048)
    gemm_nt<0><<<dim3(32, 16), 256, 0, stream>>>(xz, 4096, W_out, DINNER,
                                                 nullptr, out, DMODEL,
                                                 MROWS, DMODEL, DINNER);
}

// Round 2
// 770.409 us; speedup vs baseline: 1.8609x; 1.8609x over previous
//
#include <hip/hip_runtime.h>
#include <hip/hip_bf16.h>
#include <math.h>

// Problem constants
#define B_SZ   2
#define LSEQ   1024
#define DMODEL 1024
#define DSTATE 16
#define DCONV  4
#define DINNER 2048
#define MROWS  (B_SZ * LSEQ)        // 2048
#define NCHUNK 32
#define TCHUNK (LSEQ / NCHUNK)      // 32

// ---------------- fp32 tiled GEMM: C[m,n] = sum_k A[m,k] * Bt[n,k] ----------
template<int EPI>
__global__ __launch_bounds__(256)
void gemm_nt(const float* __restrict__ A, int lda,
             const float* __restrict__ Bt, int ldb,
             const float* __restrict__ bias,
             float* __restrict__ C, int ldc,
             int M, int N, int K)
{
    __shared__ float As[16][68];
    __shared__ float Bs[16][68];
    const int tid = threadIdx.x;
    const int m0 = blockIdx.x * 64;
    const int n0 = blockIdx.y * 64;
    const int tm = tid & 15;
    const int tn = tid >> 4;
    const int lc = tid & 3;
    const int lr = tid >> 2;

    float acc[4][4] = {};

    for (int k0 = 0; k0 < K; k0 += 16) {
        float4 av = *(const float4*)&A [(size_t)(m0 + lr) * lda + k0 + 4 * lc];
        float4 bv = *(const float4*)&Bt[(size_t)(n0 + lr) * ldb + k0 + 4 * lc];
        As[4*lc+0][lr] = av.x; As[4*lc+1][lr] = av.y;
        As[4*lc+2][lr] = av.z; As[4*lc+3][lr] = av.w;
        Bs[4*lc+0][lr] = bv.x; Bs[4*lc+1][lr] = bv.y;
        Bs[4*lc+2][lr] = bv.z; Bs[4*lc+3][lr] = bv.w;
        __syncthreads();
        #pragma unroll
        for (int k = 0; k < 16; ++k) {
            float a[4], b[4];
            #pragma unroll
            for (int i = 0; i < 4; ++i) a[i] = As[k][tm*4 + i];
            #pragma unroll
            for (int j = 0; j < 4; ++j) b[j] = Bs[k][tn*4 + j];
            #pragma unroll
            for (int i = 0; i < 4; ++i)
                #pragma unroll
                for (int j = 0; j < 4; ++j)
                    acc[i][j] += a[i] * b[j];
        }
        __syncthreads();
    }

    #pragma unroll
    for (int i = 0; i < 4; ++i) {
        const int m = m0 + tm*4 + i;
        #pragma unroll
        for (int j = 0; j < 4; ++j) {
            const int n = n0 + tn*4 + j;
            float v = acc[i][j];
            if (EPI == 1) {
                v += bias[n];
                v = (v > 20.f) ? v : log1pf(__expf(v));
            }
            C[(size_t)m * ldc + n] = v;
        }
    }
}

// --------------- causal depthwise conv (k=4, left pad 3) + SiLU -------------
__global__ __launch_bounds__(256)
void conv_silu(const float* __restrict__ xz, const float* __restrict__ cw,
               const float* __restrict__ cb, float* __restrict__ u)
{
    int idx = blockIdx.x * blockDim.x + threadIdx.x;
    int d = idx & (DINNER - 1);
    int m = idx >> 11;
    int t = m & (LSEQ - 1);
    float acc = cb[d];
    #pragma unroll
    for (int j = 0; j < DCONV; ++j) {
        int tt = t - (DCONV - 1) + j;
        if (tt >= 0)
            acc += xz[(size_t)(m - t + tt) * 4096 + d] * cw[d * DCONV + j];
    }
    u[(size_t)m * DINNER + d] = acc / (1.f + __expf(-acc));
}

// -------------------- B/C projection: bc[m, 0:32] = u[m,:] @ Wx.T -----------
__global__ __launch_bounds__(64)
void bc_gemm(const float* __restrict__ u, const float* __restrict__ Wx,
             float* __restrict__ bc)
{
    int m = blockIdx.x;
    int lane = threadIdx.x;
    int n = lane & 31, half = lane >> 5;
    const float* ur = u  + (size_t)m * DINNER + half * (DINNER / 2);
    const float* wr = Wx + (size_t)n * DINNER + half * (DINNER / 2);
    float acc = 0.f;
    for (int k = 0; k < DINNER / 2; k += 4) {
        float4 uv = *(const float4*)&ur[k];
        float4 wv = *(const float4*)&wr[k];
        acc += uv.x*wv.x + uv.y*wv.y + uv.z*wv.z + uv.w*wv.w;
    }
    acc += __shfl_xor(acc, 32);
    if (half == 0) bc[m * 32 + n] = acc;
}

// ------------------------- chunked selective scan ---------------------------
// Phase 1: per-chunk local scan (zero init). Emits s_end[b][c][d][16] and
// dtsum[b][c][d].  Thread = (b, chunk, d); 16 n-states in registers.
__global__ __launch_bounds__(256)
void scan_part1(const float* __restrict__ dt, const float* __restrict__ u,
                const float* __restrict__ bc, const float* __restrict__ A_log,
                float* __restrict__ s_end, float* __restrict__ dtsum)
{
    const int d = blockIdx.x * 256 + threadIdx.x;
    const int c = blockIdx.y;
    const int b = blockIdx.z;
    __shared__ float bcs[TCHUNK][32];
    {
        int f = threadIdx.x * 4;
        const float* src = bc + ((size_t)b * LSEQ + c * TCHUNK) * 32;
        *(float4*)&bcs[f >> 5][f & 31] = *(const float4*)&src[f];
    }
    float An[16];
    {
        float4 a0 = *(const float4*)&A_log[d * DSTATE + 0];
        float4 a1 = *(const float4*)&A_log[d * DSTATE + 4];
        float4 a2 = *(const float4*)&A_log[d * DSTATE + 8];
        float4 a3 = *(const float4*)&A_log[d * DSTATE + 12];
        An[0]=-__expf(a0.x); An[1]=-__expf(a0.y); An[2]=-__expf(a0.z); An[3]=-__expf(a0.w);
        An[4]=-__expf(a1.x); An[5]=-__expf(a1.y); An[6]=-__expf(a1.z); An[7]=-__expf(a1.w);
        An[8]=-__expf(a2.x); An[9]=-__expf(a2.y); An[10]=-__expf(a2.z); An[11]=-__expf(a2.w);
        An[12]=-__expf(a3.x); An[13]=-__expf(a3.y); An[14]=-__expf(a3.z); An[15]=-__expf(a3.w);
    }
    __syncthreads();
    const float* dtp = dt + ((size_t)b * LSEQ + c * TCHUNK) * DINNER + d;
    const float* up  = u  + ((size_t)b * LSEQ + c * TCHUNK) * DINNER + d;
    float s[16] = {};
    float sum = 0.f;
    for (int t = 0; t < TCHUNK; ++t) {
        float dtv = dtp[(size_t)t * DINNER];
        float uv  = up [(size_t)t * DINNER];
        sum += dtv;
        float du = dtv * uv;
        #pragma unroll
        for (int n = 0; n < 16; ++n) {
            float a = __expf(dtv * An[n]);
            s[n] = a * s[n] + du * bcs[t][n];
        }
    }
    float* se = s_end + ((size_t)(b * NCHUNK + c) * DINNER + d) * 16;
    #pragma unroll
    for (int q = 0; q < 4; ++q)
        *(float4*)&se[q * 4] = make_float4(s[q*4], s[q*4+1], s[q*4+2], s[q*4+3]);
    dtsum[(size_t)(b * NCHUNK + c) * DINNER + d] = sum;
}

// Phase 2: sequential combine across chunks. Thread = (b, d, n).
// s_in[c] = state entering chunk c;  S_{c+1} = exp(An*dtsum_c)*S_c + s_end_c.
__global__ __launch_bounds__(256)
void scan_combine(const float* __restrict__ s_end, const float* __restrict__ dtsum,
                  const float* __restrict__ A_log, float* __restrict__ s_in)
{
    int idx = blockIdx.x * 256 + threadIdx.x;   // b*32768 + d*16 + n
    int n = idx & 15;
    int d = (idx >> 4) & (DINNER - 1);
    int b = idx >> 15;
    float An = -__expf(A_log[d * DSTATE + n]);
    float s = 0.f;
    for (int c = 0; c < NCHUNK; ++c) {
        size_t base = (size_t)(b * NCHUNK + c) * DINNER + d;
        s_in[base * 16 + n] = s;
        float P = __expf(An * dtsum[base]);
        s = P * s + s_end[base * 16 + n];
    }
}

// Phase 3: full local scan seeded with s_in; fuses y = sum_n s*C + D*u and
// the silu(z) gate; writes gated y into the xi half of xz.
__global__ __launch_bounds__(256)
void scan_part2(const float* __restrict__ dt, const float* __restrict__ u,
                const float* __restrict__ bc, const float* __restrict__ s_in,
                const float* __restrict__ A_log, const float* __restrict__ Dp,
                float* __restrict__ xz)
{
    const int d = blockIdx.x * 256 + threadIdx.x;
    const int c = blockIdx.y;
    const int b = blockIdx.z;
    __shared__ float bcs[TCHUNK][32];
    {
        int f = threadIdx.x * 4;
        const float* src = bc + ((size_t)b * LSEQ + c * TCHUNK) * 32;
        *(float4*)&bcs[f >> 5][f & 31] = *(const float4*)&src[f];
    }
    float An[16];
    {
        float4 a0 = *(const float4*)&A_log[d * DSTATE + 0];
        float4 a1 = *(const float4*)&A_log[d * DSTATE + 4];
        float4 a2 = *(const float4*)&A_log[d * DSTATE + 8];
        float4 a3 = *(const float4*)&A_log[d * DSTATE + 12];
        An[0]=-__expf(a0.x); An[1]=-__expf(a0.y); An[2]=-__expf(a0.z); An[3]=-__expf(a0.w);
        An[4]=-__expf(a1.x); An[5]=-__expf(a1.y); An[6]=-__expf(a1.z); An[7]=-__expf(a1.w);
        An[8]=-__expf(a2.x); An[9]=-__expf(a2.y); An[10]=-__expf(a2.z); An[11]=-__expf(a2.w);
        An[12]=-__expf(a3.x); An[13]=-__expf(a3.y); An[14]=-__expf(a3.z); An[15]=-__expf(a3.w);
    }
    float s[16];
    {
        const float* si = s_in + ((size_t)(b * NCHUNK + c) * DINNER + d) * 16;
        #pragma unroll
        for (int q = 0; q < 4; ++q) {
            float4 v = *(const float4*)&si[q * 4];
            s[q*4] = v.x; s[q*4+1] = v.y; s[q*4+2] = v.z; s[q*4+3] = v.w;
        }
    }
    const float Dd = Dp[d];
    __syncthreads();
    const float* dtp = dt + ((size_t)b * LSEQ + c * TCHUNK) * DINNER + d;
    const float* up  = u  + ((size_t)b * LSEQ + c * TCHUNK) * DINNER + d;
    float* xzb = xz + ((size_t)b * LSEQ + c * TCHUNK) * 4096 + d;
    for (int t = 0; t < TCHUNK; ++t) {
        float dtv = dtp[(size_t)t * DINNER];
        float uv  = up [(size_t)t * DINNER];
        float du = dtv * uv;
        float y = Dd * uv;
        #pragma unroll
        for (int n = 0; n < 16; ++n) {
            float a = __expf(dtv * An[n]);
            s[n] = a * s[n] + du * bcs[t][n];
            y += s[n] * bcs[t][16 + n];
        }
        float zv = xzb[(size_t)t * 4096 + 2048];
        xzb[(size_t)t * 4096] = y * (zv / (1.f + __expf(-zv)));
    }
}

// ---------------------------------------------------------------------------
extern "C" void kernel_launch(void* const* d_in, const int* in_sizes, int n_in,
                              void* d_out, int out_size, void* d_ws, size_t ws_size,
                              hipStream_t stream)
{
    const float* x      = (const float*)d_in[0];
    const float* W_in   = (const float*)d_in[1];
    const float* conv_w = (const float*)d_in[2];
    const float* conv_b = (const float*)d_in[3];
    const float* W_x    = (const float*)d_in[4];
    const float* W_dt   = (const float*)d_in[5];
    const float* b_dt   = (const float*)d_in[6];
    const float* A_log  = (const float*)d_in[7];
    const float* Dp     = (const float*)d_in[8];
    const float* W_out  = (const float*)d_in[9];
    float* out = (float*)d_out;

    float* ws = (float*)d_ws;
    float* xz    = ws;                                    // 2048 x 4096
    float* u     = xz    + (size_t)MROWS * 4096;          // 2048 x 2048
    float* dt    = u     + (size_t)MROWS * DINNER;        // 2048 x 2048
    float* bc    = dt    + (size_t)MROWS * DINNER;        // 2048 x 32
    float* s_end = bc    + (size_t)MROWS * 32;            // 2*32*2048*16
    float* s_in  = s_end + (size_t)B_SZ * NCHUNK * DINNER * 16;
    float* dtsum = s_in  + (size_t)B_SZ * NCHUNK * DINNER * 16;  // 2*32*2048

    // 1. xz = x @ W_in.T           (M=2048, N=4096, K=1024)
    gemm_nt<0><<<dim3(32, 64), 256, 0, stream>>>(x, DMODEL, W_in, DMODEL,
                                                 nullptr, xz, 4096,
                                                 MROWS, 4096, DMODEL);
    // 2. u = silu(causal_conv(xi) + conv_b)
    conv_silu<<<(MROWS * DINNER) / 256, 256, 0, stream>>>(xz, conv_w, conv_b, u);
    // 3. dt = softplus(u @ W_dt.T + b_dt)   (M=2048, N=2048, K=2048)
    gemm_nt<1><<<dim3(32, 32), 256, 0, stream>>>(u, DINNER, W_dt, DINNER,
                                                 b_dt, dt, DINNER,
                                                 MROWS, DINNER, DINNER);
    // 4. bc = u @ W_x.T
    bc_gemm<<<MROWS, 64, 0, stream>>>(u, W_x, bc);
    // 5. chunked scan
    scan_part1<<<dim3(DINNER/256, NCHUNK, B_SZ), 256, 0, stream>>>(
        dt, u, bc, A_log, s_end, dtsum);
    scan_combine<<<(B_SZ * DINNER * DSTATE) / 256, 256, 0, stream>>>(
        s_end, dtsum, A_log, s_in);
    scan_part2<<<dim3(DINNER/256, NCHUNK, B_SZ), 256, 0, stream>>>(
        dt, u, bc, s_in, A_log, Dp, xz);
    // 6. out = y @ W_out.T         (M=2048, N=1024, K=2048)
    gemm_nt<0><<<dim3(32, 16), 256, 0, stream>>>(xz, 4096, W_out, DINNER,
                                                 nullptr, out, DMODEL,
                                                 MROWS, DMODEL, DINNER);
}

// Round 3
// 305.610 us; speedup vs baseline: 4.6911x; 2.5209x over previous
//
#include <hip/hip_runtime.h>
#include <hip/hip_bf16.h>
#include <math.h>

// Problem constants
#define B_SZ   2
#define LSEQ   1024
#define DMODEL 1024
#define DSTATE 16
#define DCONV  4
#define DINNER 2048
#define MROWS  (B_SZ * LSEQ)        // 2048
#define NCHUNK 32
#define TCHUNK (LSEQ / NCHUNK)      // 32

typedef __attribute__((ext_vector_type(8))) short bf16x8;
typedef __attribute__((ext_vector_type(4))) float f32x4;

__device__ __forceinline__ void gl2lds16(const void* g, void* l) {
    __builtin_amdgcn_global_load_lds(
        (const __attribute__((address_space(1))) void*)g,
        (__attribute__((address_space(3))) void*)l, 16, 0, 0);
}

// ------------------------- fp32 -> bf16 conversion --------------------------
__global__ __launch_bounds__(256)
void cvt_bf16(const float* __restrict__ in, __hip_bfloat16* __restrict__ out)
{
    int i = (blockIdx.x * 256 + threadIdx.x) * 8;
    float4 a = *(const float4*)&in[i];
    float4 b = *(const float4*)&in[i + 4];
    union { __hip_bfloat16 h[8]; int4 v; } o;
    o.h[0] = __float2bfloat16(a.x); o.h[1] = __float2bfloat16(a.y);
    o.h[2] = __float2bfloat16(a.z); o.h[3] = __float2bfloat16(a.w);
    o.h[4] = __float2bfloat16(b.x); o.h[5] = __float2bfloat16(b.y);
    o.h[6] = __float2bfloat16(b.z); o.h[7] = __float2bfloat16(b.w);
    *(int4*)&out[i] = o.v;
}

// ------------- bf16 MFMA GEMM (m97 structure): C = A @ B^T ------------------
// A: M x K row-major bf16, B: N x K row-major bf16, C fp32.
// 128x128 tile, 4 waves, each wave 64x64 (4x4 frags of 16x16x32).
// EPI: 0 = none, 1 = softplus(x + bias[n])
template<int EPI>
__global__ __launch_bounds__(256)
void gemm_bt_mfma(const __hip_bfloat16* __restrict__ A,
                  const __hip_bfloat16* __restrict__ B,
                  const float* __restrict__ bias,
                  float* __restrict__ C, int ldc,
                  int M, int N, int K)
{
    __shared__ __hip_bfloat16 As[128 * 32];
    __shared__ __hip_bfloat16 Bs[128 * 32];
    const int tid  = threadIdx.x;
    const int lane = tid & 63;
    const int w    = tid >> 6;
    const int m0 = blockIdx.x * 128;
    const int n0 = blockIdx.y * 128;
    const int wr = w >> 1, wc = w & 1;

    // staging: chunk q = w*2 + h covers LDS bytes [q*1024,(q+1)*1024)
    // = rows q*16 .. q*16+15 (row = 64B). lane -> row q*16 + lane/4,
    // col element (lane&3)*8.  HW writes LDS base + lane*16.
    const int srow = w * 32 + (lane >> 2);
    const int scol = (lane & 3) * 8;
    const __hip_bfloat16* Asrc0 = A + (size_t)(m0 + srow) * K + scol;
    const __hip_bfloat16* Asrc1 = Asrc0 + (size_t)16 * K;
    const __hip_bfloat16* Bsrc0 = B + (size_t)(n0 + srow) * K + scol;
    const __hip_bfloat16* Bsrc1 = Bsrc0 + (size_t)16 * K;
    __hip_bfloat16* Adst0 = As + w * 1024;      // wave-uniform
    __hip_bfloat16* Adst1 = Adst0 + 512;
    __hip_bfloat16* Bdst0 = Bs + w * 1024;
    __hip_bfloat16* Bdst1 = Bdst0 + 512;

    f32x4 acc[4][4] = {};

    for (int k0 = 0; k0 < K; k0 += 32) {
        gl2lds16(Asrc0 + k0, Adst0);
        gl2lds16(Asrc1 + k0, Adst1);
        gl2lds16(Bsrc0 + k0, Bdst0);
        gl2lds16(Bsrc1 + k0, Bdst1);
        __syncthreads();

        bf16x8 af[4], bfr[4];
        const int ar = (wr * 64 + (lane & 15)) * 32 + (lane >> 4) * 8;
        const int br = (wc * 64 + (lane & 15)) * 32 + (lane >> 4) * 8;
        #pragma unroll
        for (int m = 0; m < 4; ++m)
            af[m] = *(const bf16x8*)&As[ar + m * 16 * 32];
        #pragma unroll
        for (int n = 0; n < 4; ++n)
            bfr[n] = *(const bf16x8*)&Bs[br + n * 16 * 32];
        #pragma unroll
        for (int m = 0; m < 4; ++m)
            #pragma unroll
            for (int n = 0; n < 4; ++n)
                acc[m][n] = __builtin_amdgcn_mfma_f32_16x16x32_bf16(
                    af[m], bfr[n], acc[m][n], 0, 0, 0);
        __syncthreads();
    }

    #pragma unroll
    for (int m = 0; m < 4; ++m) {
        #pragma unroll
        for (int n = 0; n < 4; ++n) {
            const int col = n0 + wc * 64 + n * 16 + (lane & 15);
            const float bv = (EPI == 1) ? bias[col] : 0.f;
            #pragma unroll
            for (int j = 0; j < 4; ++j) {
                const int row = m0 + wr * 64 + m * 16 + (lane >> 4) * 4 + j;
                float v = acc[m][n][j];
                if (EPI == 1) {
                    v += bv;
                    v = (v > 20.f) ? v : log1pf(__expf(v));
                }
                C[(size_t)row * ldc + col] = v;
            }
        }
    }
}

// --------------- causal depthwise conv (k=4, left pad 3) + SiLU -------------
// Also emits bf16 copy of u for the dt MFMA GEMM.
__global__ __launch_bounds__(256)
void conv_silu(const float* __restrict__ xz, const float* __restrict__ cw,
               const float* __restrict__ cb, float* __restrict__ u,
               __hip_bfloat16* __restrict__ u_bf)
{
    int idx = blockIdx.x * blockDim.x + threadIdx.x;
    int d = idx & (DINNER - 1);
    int m = idx >> 11;
    int t = m & (LSEQ - 1);
    float acc = cb[d];
    #pragma unroll
    for (int j = 0; j < DCONV; ++j) {
        int tt = t - (DCONV - 1) + j;
        if (tt >= 0)
            acc += xz[(size_t)(m - t + tt) * 4096 + d] * cw[d * DCONV + j];
    }
    float v = acc / (1.f + __expf(-acc));
    u[(size_t)m * DINNER + d] = v;
    u_bf[(size_t)m * DINNER + d] = __float2bfloat16(v);
}

// -------------------- B/C projection: bc[m, 0:32] = u[m,:] @ Wx.T -----------
// 4 waves per block, wave per row.
__global__ __launch_bounds__(256)
void bc_gemm(const float* __restrict__ u, const float* __restrict__ Wx,
             float* __restrict__ bc)
{
    int m = blockIdx.x * 4 + (threadIdx.x >> 6);
    int lane = threadIdx.x & 63;
    int n = lane & 31, half = lane >> 5;
    const float* ur = u  + (size_t)m * DINNER + half * (DINNER / 2);
    const float* wr = Wx + (size_t)n * DINNER + half * (DINNER / 2);
    float acc = 0.f;
    for (int k = 0; k < DINNER / 2; k += 4) {
        float4 uv = *(const float4*)&ur[k];
        float4 wv = *(const float4*)&wr[k];
        acc += uv.x*wv.x + uv.y*wv.y + uv.z*wv.z + uv.w*wv.w;
    }
    acc += __shfl_xor(acc, 32);
    if (half == 0) bc[m * 32 + n] = acc;
}

// ------------------------- chunked selective scan ---------------------------
__global__ __launch_bounds__(256)
void scan_part1(const float* __restrict__ dt, const float* __restrict__ u,
                const float* __restrict__ bc, const float* __restrict__ A_log,
                float* __restrict__ s_end, float* __restrict__ dtsum)
{
    const int d = blockIdx.x * 256 + threadIdx.x;
    const int c = blockIdx.y;
    const int b = blockIdx.z;
    __shared__ float bcs[TCHUNK][32];
    {
        int f = threadIdx.x * 4;
        const float* src = bc + ((size_t)b * LSEQ + c * TCHUNK) * 32;
        *(float4*)&bcs[f >> 5][f & 31] = *(const float4*)&src[f];
    }
    float An[16];
    {
        float4 a0 = *(const float4*)&A_log[d * DSTATE + 0];
        float4 a1 = *(const float4*)&A_log[d * DSTATE + 4];
        float4 a2 = *(const float4*)&A_log[d * DSTATE + 8];
        float4 a3 = *(const float4*)&A_log[d * DSTATE + 12];
        An[0]=-__expf(a0.x); An[1]=-__expf(a0.y); An[2]=-__expf(a0.z); An[3]=-__expf(a0.w);
        An[4]=-__expf(a1.x); An[5]=-__expf(a1.y); An[6]=-__expf(a1.z); An[7]=-__expf(a1.w);
        An[8]=-__expf(a2.x); An[9]=-__expf(a2.y); An[10]=-__expf(a2.z); An[11]=-__expf(a2.w);
        An[12]=-__expf(a3.x); An[13]=-__expf(a3.y); An[14]=-__expf(a3.z); An[15]=-__expf(a3.w);
    }
    __syncthreads();
    const float* dtp = dt + ((size_t)b * LSEQ + c * TCHUNK) * DINNER + d;
    const float* up  = u  + ((size_t)b * LSEQ + c * TCHUNK) * DINNER + d;
    float s[16] = {};
    float sum = 0.f;
    for (int t = 0; t < TCHUNK; ++t) {
        float dtv = dtp[(size_t)t * DINNER];
        float uv  = up [(size_t)t * DINNER];
        sum += dtv;
        float du = dtv * uv;
        #pragma unroll
        for (int n = 0; n < 16; ++n) {
            float a = __expf(dtv * An[n]);
            s[n] = a * s[n] + du * bcs[t][n];
        }
    }
    float* se = s_end + ((size_t)(b * NCHUNK + c) * DINNER + d) * 16;
    #pragma unroll
    for (int q = 0; q < 4; ++q)
        *(float4*)&se[q * 4] = make_float4(s[q*4], s[q*4+1], s[q*4+2], s[q*4+3]);
    dtsum[(size_t)(b * NCHUNK + c) * DINNER + d] = sum;
}

// In-place combine: s_end[c] (chunk-local end state) -> state ENTERING chunk c.
__global__ __launch_bounds__(256)
void scan_combine(float* __restrict__ s_end, const float* __restrict__ dtsum,
                  const float* __restrict__ A_log)
{
    int idx = blockIdx.x * 256 + threadIdx.x;   // b*32768 + d*16 + n
    int n = idx & 15;
    int d = (idx >> 4) & (DINNER - 1);
    int b = idx >> 15;
    float An = -__expf(A_log[d * DSTATE + n]);
    float s = 0.f;
    for (int c = 0; c < NCHUNK; ++c) {
        size_t base = (size_t)(b * NCHUNK + c) * DINNER + d;
        float se = s_end[base * 16 + n];
        s_end[base * 16 + n] = s;
        float P = __expf(An * dtsum[base]);
        s = P * s + se;
    }
}

// Phase 3: local scan seeded with s_in (= transformed s_end); fuses
// y = sum_n s*C + D*u and silu(z) gate; emits gated y as bf16.
__global__ __launch_bounds__(256)
void scan_part2(const float* __restrict__ dt, const float* __restrict__ u,
                const float* __restrict__ bc, const float* __restrict__ s_in,
                const float* __restrict__ A_log, const float* __restrict__ Dp,
                const float* __restrict__ xz, __hip_bfloat16* __restrict__ y_bf)
{
    const int d = blockIdx.x * 256 + threadIdx.x;
    const int c = blockIdx.y;
    const int b = blockIdx.z;
    __shared__ float bcs[TCHUNK][32];
    {
        int f = threadIdx.x * 4;
        const float* src = bc + ((size_t)b * LSEQ + c * TCHUNK) * 32;
        *(float4*)&bcs[f >> 5][f & 31] = *(const float4*)&src[f];
    }
    float An[16];
    {
        float4 a0 = *(const float4*)&A_log[d * DSTATE + 0];
        float4 a1 = *(const float4*)&A_log[d * DSTATE + 4];
        float4 a2 = *(const float4*)&A_log[d * DSTATE + 8];
        float4 a3 = *(const float4*)&A_log[d * DSTATE + 12];
        An[0]=-__expf(a0.x); An[1]=-__expf(a0.y); An[2]=-__expf(a0.z); An[3]=-__expf(a0.w);
        An[4]=-__expf(a1.x); An[5]=-__expf(a1.y); An[6]=-__expf(a1.z); An[7]=-__expf(a1.w);
        An[8]=-__expf(a2.x); An[9]=-__expf(a2.y); An[10]=-__expf(a2.z); An[11]=-__expf(a2.w);
        An[12]=-__expf(a3.x); An[13]=-__expf(a3.y); An[14]=-__expf(a3.z); An[15]=-__expf(a3.w);
    }
    float s[16];
    {
        const float* si = s_in + ((size_t)(b * NCHUNK + c) * DINNER + d) * 16;
        #pragma unroll
        for (int q = 0; q < 4; ++q) {
            float4 v = *(const float4*)&si[q * 4];
            s[q*4] = v.x; s[q*4+1] = v.y; s[q*4+2] = v.z; s[q*4+3] = v.w;
        }
    }
    const float Dd = Dp[d];
    __syncthreads();
    const float* dtp = dt + ((size_t)b * LSEQ + c * TCHUNK) * DINNER + d;
    const float* up  = u  + ((size_t)b * LSEQ + c * TCHUNK) * DINNER + d;
    const float* zp  = xz + ((size_t)b * LSEQ + c * TCHUNK) * 4096 + 2048 + d;
    __hip_bfloat16* yp = y_bf + ((size_t)b * LSEQ + c * TCHUNK) * DINNER + d;
    for (int t = 0; t < TCHUNK; ++t) {
        float dtv = dtp[(size_t)t * DINNER];
        float uv  = up [(size_t)t * DINNER];
        float du = dtv * uv;
        float y = Dd * uv;
        #pragma unroll
        for (int n = 0; n < 16; ++n) {
            float a = __expf(dtv * An[n]);
            s[n] = a * s[n] + du * bcs[t][n];
            y += s[n] * bcs[t][16 + n];
        }
        float zv = zp[(size_t)t * 4096];
        yp[(size_t)t * DINNER] = __float2bfloat16(y * (zv / (1.f + __expf(-zv))));
    }
}

// ---------------------------------------------------------------------------
extern "C" void kernel_launch(void* const* d_in, const int* in_sizes, int n_in,
                              void* d_out, int out_size, void* d_ws, size_t ws_size,
                              hipStream_t stream)
{
    const float* x      = (const float*)d_in[0];
    const float* W_in   = (const float*)d_in[1];
    const float* conv_w = (const float*)d_in[2];
    const float* conv_b = (const float*)d_in[3];
    const float* W_x    = (const float*)d_in[4];
    const float* W_dt   = (const float*)d_in[5];
    const float* b_dt   = (const float*)d_in[6];
    const float* A_log  = (const float*)d_in[7];
    const float* Dp     = (const float*)d_in[8];
    const float* W_out  = (const float*)d_in[9];
    float* out = (float*)d_out;

    const size_t MB = 1ull << 20;
    char* w8 = (char*)d_ws;
    float* xz    = (float*)(w8);              // 32MB  (2048 x 4096)
    float* u     = (float*)(w8 + 32*MB);      // 16MB
    float* dt    = (float*)(w8 + 48*MB);      // 16MB
    float* bc    = (float*)(w8 + 64*MB);      // 0.25MB
    float* sbuf  = (float*)(w8 + 65*MB);      // 8MB   s_end -> s_in (in place)
    float* dtsum = (float*)(w8 + 73*MB);      // 0.5MB
    __hip_bfloat16* u_bf   = (__hip_bfloat16*)(w8 + 74*MB);  // 8MB
    // region X (12MB at +82MB), time-multiplexed:
    __hip_bfloat16* x_bf   = (__hip_bfloat16*)(w8 + 82*MB);  // 4MB  (GEMM1)
    __hip_bfloat16* Win_bf = (__hip_bfloat16*)(w8 + 86*MB);  // 8MB  (GEMM1)
    __hip_bfloat16* Wdt_bf = (__hip_bfloat16*)(w8 + 82*MB);  // 8MB  (GEMM2)
    __hip_bfloat16* Wout_bf= (__hip_bfloat16*)(w8 + 90*MB);  // 4MB  (GEMM3)
    __hip_bfloat16* y_bf   = (__hip_bfloat16*)(w8 + 82*MB);  // 8MB  (GEMM3)

    // 0. convert GEMM1 inputs
    cvt_bf16<<<(MROWS * DMODEL) / (256 * 8), 256, 0, stream>>>(x, x_bf);
    cvt_bf16<<<(4096 * DMODEL) / (256 * 8), 256, 0, stream>>>(W_in, Win_bf);
    // 1. xz = x @ W_in.T           (M=2048, N=4096, K=1024)
    gemm_bt_mfma<0><<<dim3(16, 32), 256, 0, stream>>>(x_bf, Win_bf, nullptr,
                                                      xz, 4096, MROWS, 4096, DMODEL);
    // 2. u = silu(causal_conv(xi) + conv_b)  (+ bf16 copy)
    conv_silu<<<(MROWS * DINNER) / 256, 256, 0, stream>>>(xz, conv_w, conv_b, u, u_bf);
    // 2b. convert GEMM2/GEMM3 weights (region X free after GEMM1)
    cvt_bf16<<<(DINNER * DINNER) / (256 * 8), 256, 0, stream>>>(W_dt, Wdt_bf);
    cvt_bf16<<<(DMODEL * DINNER) / (256 * 8), 256, 0, stream>>>(W_out, Wout_bf);
    // 3. dt = softplus(u @ W_dt.T + b_dt)   (M=2048, N=2048, K=2048)
    gemm_bt_mfma<1><<<dim3(16, 16), 256, 0, stream>>>(u_bf, Wdt_bf, b_dt,
                                                      dt, DINNER, MROWS, DINNER, DINNER);
    // 4. bc = u @ W_x.T
    bc_gemm<<<MROWS / 4, 256, 0, stream>>>(u, W_x, bc);
    // 5. chunked scan (writes gated y as bf16; Wdt_bf dead by then)
    scan_part1<<<dim3(DINNER/256, NCHUNK, B_SZ), 256, 0, stream>>>(
        dt, u, bc, A_log, sbuf, dtsum);
    scan_combine<<<(B_SZ * DINNER * DSTATE) / 256, 256, 0, stream>>>(
        sbuf, dtsum, A_log);
    scan_part2<<<dim3(DINNER/256, NCHUNK, B_SZ), 256, 0, stream>>>(
        dt, u, bc, sbuf, A_log, Dp, xz, y_bf);
    // 6. out = y @ W_out.T         (M=2048, N=1024, K=2048)
    gemm_bt_mfma<0><<<dim3(16, 8), 256, 0, stream>>>(y_bf, Wout_bf, nullptr,
                                                     out, DMODEL, MROWS, DMODEL, DINNER);
}

// Round 4
// 246.539 us; speedup vs baseline: 5.8151x; 1.2396x over previous
//
#include <hip/hip_runtime.h>
#include <hip/hip_bf16.h>
#include <math.h>

// Problem constants
#define B_SZ   2
#define LSEQ   1024
#define DMODEL 1024
#define DSTATE 16
#define DCONV  4
#define DINNER 2048
#define MROWS  (B_SZ * LSEQ)        // 2048
#define NCHUNK 32
#define TCHUNK (LSEQ / NCHUNK)      // 32
#define NCAT   2176                 // 2048 (W_dt) + 32 (W_x) + 96 pad

typedef __attribute__((ext_vector_type(8))) short bf16x8;
typedef __attribute__((ext_vector_type(4))) float f32x4;

__device__ __forceinline__ void gl2lds16(const void* g, void* l) {
    __builtin_amdgcn_global_load_lds(
        (const __attribute__((address_space(1))) void*)g,
        (__attribute__((address_space(3))) void*)l, 16, 0, 0);
}

// ------------------------- fp32 -> bf16 conversion --------------------------
__global__ __launch_bounds__(256)
void cvt_bf16(const float* __restrict__ in, __hip_bfloat16* __restrict__ out)
{
    int i = (blockIdx.x * 256 + threadIdx.x) * 8;
    float4 a = *(const float4*)&in[i];
    float4 b = *(const float4*)&in[i + 4];
    union { __hip_bfloat16 h[8]; int4 v; } o;
    o.h[0] = __float2bfloat16(a.x); o.h[1] = __float2bfloat16(a.y);
    o.h[2] = __float2bfloat16(a.z); o.h[3] = __float2bfloat16(a.w);
    o.h[4] = __float2bfloat16(b.x); o.h[5] = __float2bfloat16(b.y);
    o.h[6] = __float2bfloat16(b.z); o.h[7] = __float2bfloat16(b.w);
    *(int4*)&out[i] = o.v;
}

// ------------- bf16 MFMA GEMM (m97 structure): C = A @ B^T ------------------
// A: M x K row-major bf16, B: N x K row-major bf16, C fp32.
// 128x128 tile, 4 waves, each wave 64x64 (4x4 frags of 16x16x32).
// EPI 0: C[row*ldc+col] = v
// EPI 2: col<DINNER -> softplus(v+bias[col]) into C; col in [DINNER,DINNER+32)
//        -> v into C2[row*32 + col-DINNER]; else dropped.
template<int EPI>
__global__ __launch_bounds__(256)
void gemm_bt_mfma(const __hip_bfloat16* __restrict__ A,
                  const __hip_bfloat16* __restrict__ B,
                  const float* __restrict__ bias,
                  float* __restrict__ C, int ldc,
                  float* __restrict__ C2,
                  int M, int N, int K)
{
    __shared__ __hip_bfloat16 As[128 * 32];
    __shared__ __hip_bfloat16 Bs[128 * 32];
    const int tid  = threadIdx.x;
    const int lane = tid & 63;
    const int w    = tid >> 6;
    const int m0 = blockIdx.x * 128;
    const int n0 = blockIdx.y * 128;
    const int wr = w >> 1, wc = w & 1;

    const int srow = w * 32 + (lane >> 2);
    const int scol = (lane & 3) * 8;
    const __hip_bfloat16* Asrc0 = A + (size_t)(m0 + srow) * K + scol;
    const __hip_bfloat16* Asrc1 = Asrc0 + (size_t)16 * K;
    const __hip_bfloat16* Bsrc0 = B + (size_t)(n0 + srow) * K + scol;
    const __hip_bfloat16* Bsrc1 = Bsrc0 + (size_t)16 * K;
    __hip_bfloat16* Adst0 = As + w * 1024;
    __hip_bfloat16* Adst1 = Adst0 + 512;
    __hip_bfloat16* Bdst0 = Bs + w * 1024;
    __hip_bfloat16* Bdst1 = Bdst0 + 512;

    f32x4 acc[4][4] = {};

    for (int k0 = 0; k0 < K; k0 += 32) {
        gl2lds16(Asrc0 + k0, Adst0);
        gl2lds16(Asrc1 + k0, Adst1);
        gl2lds16(Bsrc0 + k0, Bdst0);
        gl2lds16(Bsrc1 + k0, Bdst1);
        __syncthreads();

        bf16x8 af[4], bfr[4];
        const int ar = (wr * 64 + (lane & 15)) * 32 + (lane >> 4) * 8;
        const int br = (wc * 64 + (lane & 15)) * 32 + (lane >> 4) * 8;
        #pragma unroll
        for (int m = 0; m < 4; ++m)
            af[m] = *(const bf16x8*)&As[ar + m * 16 * 32];
        #pragma unroll
        for (int n = 0; n < 4; ++n)
            bfr[n] = *(const bf16x8*)&Bs[br + n * 16 * 32];
        #pragma unroll
        for (int m = 0; m < 4; ++m)
            #pragma unroll
            for (int n = 0; n < 4; ++n)
                acc[m][n] = __builtin_amdgcn_mfma_f32_16x16x32_bf16(
                    af[m], bfr[n], acc[m][n], 0, 0, 0);
        __syncthreads();
    }

    #pragma unroll
    for (int m = 0; m < 4; ++m) {
        #pragma unroll
        for (int n = 0; n < 4; ++n) {
            const int col = n0 + wc * 64 + n * 16 + (lane & 15);
            #pragma unroll
            for (int j = 0; j < 4; ++j) {
                const int row = m0 + wr * 64 + m * 16 + (lane >> 4) * 4 + j;
                float v = acc[m][n][j];
                if (EPI == 0) {
                    C[(size_t)row * ldc + col] = v;
                } else {  // EPI == 2: fused dt + bc epilogue
                    if (col < DINNER) {
                        v += bias[col];
                        v = (v > 20.f) ? v : log1pf(__expf(v));
                        C[(size_t)row * ldc + col] = v;
                    } else if (col < DINNER + 32) {
                        C2[(size_t)row * 32 + (col - DINNER)] = v;
                    }
                }
            }
        }
    }
}

// --------------- causal depthwise conv (k=4, left pad 3) + SiLU -------------
// Also emits bf16 copy of u for the fused dt/bc MFMA GEMM.
__global__ __launch_bounds__(256)
void conv_silu(const float* __restrict__ xz, const float* __restrict__ cw,
               const float* __restrict__ cb, float* __restrict__ u,
               __hip_bfloat16* __restrict__ u_bf)
{
    int idx = blockIdx.x * blockDim.x + threadIdx.x;
    int d = idx & (DINNER - 1);
    int m = idx >> 11;
    int t = m & (LSEQ - 1);
    float acc = cb[d];
    #pragma unroll
    for (int j = 0; j < DCONV; ++j) {
        int tt = t - (DCONV - 1) + j;
        if (tt >= 0)
            acc += xz[(size_t)(m - t + tt) * 4096 + d] * cw[d * DCONV + j];
    }
    float v = acc / (1.f + __expf(-acc));
    u[(size_t)m * DINNER + d] = v;
    u_bf[(size_t)m * DINNER + d] = __float2bfloat16(v);
}

// ------------------------- chunked selective scan ---------------------------
__global__ __launch_bounds__(256)
void scan_part1(const float* __restrict__ dt, const float* __restrict__ u,
                const float* __restrict__ bc, const float* __restrict__ A_log,
                float* __restrict__ s_end, float* __restrict__ dtsum)
{
    const int d = blockIdx.x * 256 + threadIdx.x;
    const int c = blockIdx.y;
    const int b = blockIdx.z;
    __shared__ float bcs[TCHUNK][32];
    {
        int f = threadIdx.x * 4;
        const float* src = bc + ((size_t)b * LSEQ + c * TCHUNK) * 32;
        *(float4*)&bcs[f >> 5][f & 31] = *(const float4*)&src[f];
    }
    float An[16];
    {
        float4 a0 = *(const float4*)&A_log[d * DSTATE + 0];
        float4 a1 = *(const float4*)&A_log[d * DSTATE + 4];
        float4 a2 = *(const float4*)&A_log[d * DSTATE + 8];
        float4 a3 = *(const float4*)&A_log[d * DSTATE + 12];
        An[0]=-__expf(a0.x); An[1]=-__expf(a0.y); An[2]=-__expf(a0.z); An[3]=-__expf(a0.w);
        An[4]=-__expf(a1.x); An[5]=-__expf(a1.y); An[6]=-__expf(a1.z); An[7]=-__expf(a1.w);
        An[8]=-__expf(a2.x); An[9]=-__expf(a2.y); An[10]=-__expf(a2.z); An[11]=-__expf(a2.w);
        An[12]=-__expf(a3.x); An[13]=-__expf(a3.y); An[14]=-__expf(a3.z); An[15]=-__expf(a3.w);
    }
    __syncthreads();
    const float* dtp = dt + ((size_t)b * LSEQ + c * TCHUNK) * DINNER + d;
    const float* up  = u  + ((size_t)b * LSEQ + c * TCHUNK) * DINNER + d;
    float s[16] = {};
    float sum = 0.f;
    for (int t = 0; t < TCHUNK; ++t) {
        float dtv = dtp[(size_t)t * DINNER];
        float uv  = up [(size_t)t * DINNER];
        sum += dtv;
        float du = dtv * uv;
        #pragma unroll
        for (int n = 0; n < 16; ++n) {
            float a = __expf(dtv * An[n]);
            s[n] = a * s[n] + du * bcs[t][n];
        }
    }
    float* se = s_end + ((size_t)(b * NCHUNK + c) * DINNER + d) * 16;
    #pragma unroll
    for (int q = 0; q < 4; ++q)
        *(float4*)&se[q * 4] = make_float4(s[q*4], s[q*4+1], s[q*4+2], s[q*4+3]);
    dtsum[(size_t)(b * NCHUNK + c) * DINNER + d] = sum;
}

// In-place combine: s_end[c] (chunk-local end state) -> state ENTERING chunk c.
__global__ __launch_bounds__(256)
void scan_combine(float* __restrict__ s_end, const float* __restrict__ dtsum,
                  const float* __restrict__ A_log)
{
    int idx = blockIdx.x * 256 + threadIdx.x;   // b*32768 + d*16 + n
    int n = idx & 15;
    int d = (idx >> 4) & (DINNER - 1);
    int b = idx >> 15;
    float An = -__expf(A_log[d * DSTATE + n]);
    float s = 0.f;
    for (int c = 0; c < NCHUNK; ++c) {
        size_t base = (size_t)(b * NCHUNK + c) * DINNER + d;
        float se = s_end[base * 16 + n];
        s_end[base * 16 + n] = s;
        float P = __expf(An * dtsum[base]);
        s = P * s + se;
    }
}

// Phase 3: local scan seeded with s_in; fuses y = sum_n s*C + D*u and the
// silu(z) gate; emits gated y as bf16.
__global__ __launch_bounds__(256)
void scan_part2(const float* __restrict__ dt, const float* __restrict__ u,
                const float* __restrict__ bc, const float* __restrict__ s_in,
                const float* __restrict__ A_log, const float* __restrict__ Dp,
                const float* __restrict__ xz, __hip_bfloat16* __restrict__ y_bf)
{
    const int d = blockIdx.x * 256 + threadIdx.x;
    const int c = blockIdx.y;
    const int b = blockIdx.z;
    __shared__ float bcs[TCHUNK][32];
    {
        int f = threadIdx.x * 4;
        const float* src = bc + ((size_t)b * LSEQ + c * TCHUNK) * 32;
        *(float4*)&bcs[f >> 5][f & 31] = *(const float4*)&src[f];
    }
    float An[16];
    {
        float4 a0 = *(const float4*)&A_log[d * DSTATE + 0];
        float4 a1 = *(const float4*)&A_log[d * DSTATE + 4];
        float4 a2 = *(const float4*)&A_log[d * DSTATE + 8];
        float4 a3 = *(const float4*)&A_log[d * DSTATE + 12];
        An[0]=-__expf(a0.x); An[1]=-__expf(a0.y); An[2]=-__expf(a0.z); An[3]=-__expf(a0.w);
        An[4]=-__expf(a1.x); An[5]=-__expf(a1.y); An[6]=-__expf(a1.z); An[7]=-__expf(a1.w);
        An[8]=-__expf(a2.x); An[9]=-__expf(a2.y); An[10]=-__expf(a2.z); An[11]=-__expf(a2.w);
        An[12]=-__expf(a3.x); An[13]=-__expf(a3.y); An[14]=-__expf(a3.z); An[15]=-__expf(a3.w);
    }
    float s[16];
    {
        const float* si = s_in + ((size_t)(b * NCHUNK + c) * DINNER + d) * 16;
        #pragma unroll
        for (int q = 0; q < 4; ++q) {
            float4 v = *(const float4*)&si[q * 4];
            s[q*4] = v.x; s[q*4+1] = v.y; s[q*4+2] = v.z; s[q*4+3] = v.w;
        }
    }
    const float Dd = Dp[d];
    __syncthreads();
    const float* dtp = dt + ((size_t)b * LSEQ + c * TCHUNK) * DINNER + d;
    const float* up  = u  + ((size_t)b * LSEQ + c * TCHUNK) * DINNER + d;
    const float* zp  = xz + ((size_t)b * LSEQ + c * TCHUNK) * 4096 + 2048 + d;
    __hip_bfloat16* yp = y_bf + ((size_t)b * LSEQ + c * TCHUNK) * DINNER + d;
    for (int t = 0; t < TCHUNK; ++t) {
        float dtv = dtp[(size_t)t * DINNER];
        float uv  = up [(size_t)t * DINNER];
        float du = dtv * uv;
        float y = Dd * uv;
        #pragma unroll
        for (int n = 0; n < 16; ++n) {
            float a = __expf(dtv * An[n]);
            s[n] = a * s[n] + du * bcs[t][n];
            y += s[n] * bcs[t][16 + n];
        }
        float zv = zp[(size_t)t * 4096];
        yp[(size_t)t * DINNER] = __float2bfloat16(y * (zv / (1.f + __expf(-zv))));
    }
}

// ---------------------------------------------------------------------------
extern "C" void kernel_launch(void* const* d_in, const int* in_sizes, int n_in,
                              void* d_out, int out_size, void* d_ws, size_t ws_size,
                              hipStream_t stream)
{
    const float* x      = (const float*)d_in[0];
    const float* W_in   = (const float*)d_in[1];
    const float* conv_w = (const float*)d_in[2];
    const float* conv_b = (const float*)d_in[3];
    const float* W_x    = (const float*)d_in[4];
    const float* W_dt   = (const float*)d_in[5];
    const float* b_dt   = (const float*)d_in[6];
    const float* A_log  = (const float*)d_in[7];
    const float* Dp     = (const float*)d_in[8];
    const float* W_out  = (const float*)d_in[9];
    float* out = (float*)d_out;

    const size_t MB = 1ull << 20;
    char* w8 = (char*)d_ws;
    float* xz    = (float*)(w8);              // 32MB  (2048 x 4096)
    float* u     = (float*)(w8 + 32*MB);      // 16MB
    float* dt    = (float*)(w8 + 48*MB);      // 16MB
    float* bc    = (float*)(w8 + 64*MB);      // 0.25MB
    float* sbuf  = (float*)(w8 + 65*MB);      // 8MB   s_end -> s_in (in place)
    float* dtsum = (float*)(w8 + 73*MB);      // 0.5MB
    __hip_bfloat16* u_bf   = (__hip_bfloat16*)(w8 + 74*MB);  // 8MB
    // region X (time-multiplexed):
    __hip_bfloat16* x_bf   = (__hip_bfloat16*)(w8 + 82*MB);  // 4MB   (GEMM1)
    __hip_bfloat16* Win_bf = (__hip_bfloat16*)(w8 + 86*MB);  // 8MB   (GEMM1)
    __hip_bfloat16* Wcat_bf= (__hip_bfloat16*)(w8 + 82*MB);  // 8.9MB (GEMM2: W_dt,W_x,pad)
    __hip_bfloat16* Wout_bf= (__hip_bfloat16*)(w8 + 91*MB);  // 4MB   (GEMM3)
    __hip_bfloat16* y_bf   = (__hip_bfloat16*)(w8 + 82*MB);  // 8MB   (GEMM3)

    // 0. convert GEMM1 inputs
    cvt_bf16<<<(MROWS * DMODEL) / (256 * 8), 256, 0, stream>>>(x, x_bf);
    cvt_bf16<<<(4096 * DMODEL) / (256 * 8), 256, 0, stream>>>(W_in, Win_bf);
    // 1. xz = x @ W_in.T           (M=2048, N=4096, K=1024)
    gemm_bt_mfma<0><<<dim3(16, 32), 256, 0, stream>>>(x_bf, Win_bf, nullptr,
                                                      xz, 4096, nullptr,
                                                      MROWS, 4096, DMODEL);
    // 2. u = silu(causal_conv(xi) + conv_b)  (+ bf16 copy)
    conv_silu<<<(MROWS * DINNER) / 256, 256, 0, stream>>>(xz, conv_w, conv_b, u, u_bf);
    // 2b. build Wcat = [W_dt; W_x] bf16 (pad rows left as garbage: their
    //     output columns are never written), and Wout bf16
    cvt_bf16<<<(DINNER * DINNER) / (256 * 8), 256, 0, stream>>>(W_dt, Wcat_bf);
    cvt_bf16<<<(32 * DINNER) / (256 * 8), 256, 0, stream>>>(W_x, Wcat_bf + (size_t)DINNER * DINNER);
    cvt_bf16<<<(DMODEL * DINNER) / (256 * 8), 256, 0, stream>>>(W_out, Wout_bf);
    // 3. fused: dt = softplus(u@W_dt.T + b_dt), bc = u@W_x.T
    //    (M=2048, N=2176, K=2048)
    gemm_bt_mfma<2><<<dim3(16, NCAT / 128), 256, 0, stream>>>(u_bf, Wcat_bf, b_dt,
                                                              dt, DINNER, bc,
                                                              MROWS, NCAT, DINNER);
    // 4. chunked scan (writes gated y as bf16; Wcat_bf dead by then)
    scan_part1<<<dim3(DINNER/256, NCHUNK, B_SZ), 256, 0, stream>>>(
        dt, u, bc, A_log, sbuf, dtsum);
    scan_combine<<<(B_SZ * DINNER * DSTATE) / 256, 256, 0, stream>>>(
        sbuf, dtsum, A_log);
    scan_part2<<<dim3(DINNER/256, NCHUNK, B_SZ), 256, 0, stream>>>(
        dt, u, bc, sbuf, A_log, Dp, xz, y_bf);
    // 5. out = y @ W_out.T         (M=2048, N=1024, K=2048)
    gemm_bt_mfma<0><<<dim3(16, 8), 256, 0, stream>>>(y_bf, Wout_bf, nullptr,
                                                     out, DMODEL, nullptr,
                                                     MROWS, DMODEL, DINNER);
}

// Round 5
// 197.209 us; speedup vs baseline: 7.2697x; 1.2501x over previous
//
#include <hip/hip_runtime.h>
#include <hip/hip_bf16.h>
#include <math.h>

// Problem constants
#define B_SZ   2
#define LSEQ   1024
#define DMODEL 1024
#define DSTATE 16
#define DCONV  4
#define DINNER 2048
#define MROWS  (B_SZ * LSEQ)        // 2048
#define NCHUNK 32
#define TCHUNK (LSEQ / NCHUNK)      // 32
#define NCAT   2176                 // 2048 (W_dt) + 32 (W_x) + 96 pad

typedef __attribute__((ext_vector_type(8))) short bf16x8;
typedef __attribute__((ext_vector_type(4))) float f32x4;

__device__ __forceinline__ void gl2lds16(const void* g, void* l) {
    __builtin_amdgcn_global_load_lds(
        (const __attribute__((address_space(1))) void*)g,
        (__attribute__((address_space(3))) void*)l, 16, 0, 0);
}

// ------------------------- fp32 -> bf16 conversion --------------------------
__global__ __launch_bounds__(256)
void cvt_bf16(const float* __restrict__ in, __hip_bfloat16* __restrict__ out)
{
    int i = (blockIdx.x * 256 + threadIdx.x) * 8;
    float4 a = *(const float4*)&in[i];
    float4 b = *(const float4*)&in[i + 4];
    union { __hip_bfloat16 h[8]; int4 v; } o;
    o.h[0] = __float2bfloat16(a.x); o.h[1] = __float2bfloat16(a.y);
    o.h[2] = __float2bfloat16(a.z); o.h[3] = __float2bfloat16(a.w);
    o.h[4] = __float2bfloat16(b.x); o.h[5] = __float2bfloat16(b.y);
    o.h[6] = __float2bfloat16(b.z); o.h[7] = __float2bfloat16(b.w);
    *(int4*)&out[i] = o.v;
}

// ---------------- bf16 MFMA GEMM, 2-phase double-buffered -------------------
// C = A @ B^T.  A: M x K bf16, B: N x K bf16 (both row-major), C fp32.
// Tile 128 x BN, 4 waves; wave tile 64 x BN/2 (4 x BN/32 frags of 16x16x32).
// Double-buffered LDS; next K-step staged via global_load_lds BEFORE compute,
// single __syncthreads per step (its vmcnt(0) drain hides under the MFMAs).
// blockIdx.z = K-split index (klen elements each); z==0 -> C0, z==1 -> C1.
// EPI 0: plain store.
// EPI 2: col<DINNER -> softplus(v+bias[col]) into C0; [DINNER,DINNER+32) -> C2.
template<int EPI, int BN>
__global__ __launch_bounds__(256)
void gemm_bt(const __hip_bfloat16* __restrict__ A,
             const __hip_bfloat16* __restrict__ B,
             const float* __restrict__ bias,
             float* __restrict__ C0, float* __restrict__ C1,
             int ldc, float* __restrict__ C2,
             int K, int klen)
{
    constexpr int NFR  = BN / 32;           // B-frags per wave
    constexpr int NCH  = (128 + BN) / 16;   // 1KB staging chunks per K-step
    constexpr int NLD  = NCH / 4;           // chunks per wave
    constexpr int SMEL = (128 + BN) * 32;   // bf16 elements per buffer
    __shared__ __hip_bfloat16 sm[2 * SMEL];

    const int tid  = threadIdx.x;
    const int lane = tid & 63;
    const int w    = tid >> 6;
    const int m0 = blockIdx.x * 128;
    const int n0 = blockIdx.y * BN;
    const int wr = w >> 1, wc = w & 1;
    const int kbase = blockIdx.z * klen;
    float* __restrict__ C = (blockIdx.z == 0) ? C0 : C1;

    // staging: chunk q (16 rows of 64B) of concatenated [A(128); B(BN)] tile
    const int lrow = lane >> 2;
    const int scol = (lane & 3) * 8;
    const __hip_bfloat16* srcp[NLD];
    #pragma unroll
    for (int i = 0; i < NLD; ++i) {
        const int q = w + 4 * i;
        srcp[i] = (q < 8)
            ? A + (size_t)(m0 + q * 16 + lrow) * K + scol + kbase
            : B + (size_t)(n0 + (q - 8) * 16 + lrow) * K + scol + kbase;
    }

    f32x4 acc[4][NFR] = {};

    // prologue: stage K-step 0 into buffer 0
    #pragma unroll
    for (int i = 0; i < NLD; ++i)
        gl2lds16(srcp[i], sm + (w + 4 * i) * 512);
    __syncthreads();

    const int nt = klen / 32;
    int cur = 0;
    for (int t = 0; t < nt; ++t) {
        if (t + 1 < nt) {                       // stage next step early
            const int nxt = cur ^ 1;
            #pragma unroll
            for (int i = 0; i < NLD; ++i)
                gl2lds16(srcp[i] + (size_t)(t + 1) * 32,
                         sm + nxt * SMEL + (w + 4 * i) * 512);
        }
        const __hip_bfloat16* As = sm + cur * SMEL;
        const __hip_bfloat16* Bs = As + 128 * 32;
        bf16x8 af[4], bfr[NFR];
        const int ar = (wr * 64 + (lane & 15)) * 32 + (lane >> 4) * 8;
        const int br = (wc * (BN / 2) + (lane & 15)) * 32 + (lane >> 4) * 8;
        #pragma unroll
        for (int m = 0; m < 4; ++m)
            af[m] = *(const bf16x8*)&As[ar + m * 16 * 32];
        #pragma unroll
        for (int n = 0; n < NFR; ++n)
            bfr[n] = *(const bf16x8*)&Bs[br + n * 16 * 32];
        #pragma unroll
        for (int m = 0; m < 4; ++m)
            #pragma unroll
            for (int n = 0; n < NFR; ++n)
                acc[m][n] = __builtin_amdgcn_mfma_f32_16x16x32_bf16(
                    af[m], bfr[n], acc[m][n], 0, 0, 0);
        __syncthreads();                        // drains vmcnt + barrier
        cur ^= 1;
    }

    #pragma unroll
    for (int m = 0; m < 4; ++m) {
        #pragma unroll
        for (int n = 0; n < NFR; ++n) {
            const int col = n0 + wc * (BN / 2) + n * 16 + (lane & 15);
            #pragma unroll
            for (int j = 0; j < 4; ++j) {
                const int row = m0 + wr * 64 + m * 16 + (lane >> 4) * 4 + j;
                float v = acc[m][n][j];
                if (EPI == 0) {
                    C[(size_t)row * ldc + col] = v;
                } else {  // EPI == 2: fused dt + bc epilogue
                    if (col < DINNER) {
                        v += bias[col];
                        v = (v > 20.f) ? v : log1pf(__expf(v));
                        C0[(size_t)row * ldc + col] = v;
                    } else if (col < DINNER + 32) {
                        C2[(size_t)row * 32 + (col - DINNER)] = v;
                    }
                }
            }
        }
    }
}

// -------------------- split-K reduce: out = p0 + p1 -------------------------
__global__ __launch_bounds__(256)
void add2(const float* __restrict__ a, const float* __restrict__ b,
          float* __restrict__ o)
{
    int i = (blockIdx.x * 256 + threadIdx.x) * 4;
    float4 va = *(const float4*)&a[i];
    float4 vb = *(const float4*)&b[i];
    va.x += vb.x; va.y += vb.y; va.z += vb.z; va.w += vb.w;
    *(float4*)&o[i] = va;
}

// --------------- causal depthwise conv (k=4, left pad 3) + SiLU -------------
__global__ __launch_bounds__(256)
void conv_silu(const float* __restrict__ xz, const float* __restrict__ cw,
               const float* __restrict__ cb, float* __restrict__ u,
               __hip_bfloat16* __restrict__ u_bf)
{
    int idx = blockIdx.x * blockDim.x + threadIdx.x;
    int d = idx & (DINNER - 1);
    int m = idx >> 11;
    int t = m & (LSEQ - 1);
    float acc = cb[d];
    #pragma unroll
    for (int j = 0; j < DCONV; ++j) {
        int tt = t - (DCONV - 1) + j;
        if (tt >= 0)
            acc += xz[(size_t)(m - t + tt) * 4096 + d] * cw[d * DCONV + j];
    }
    float v = acc / (1.f + __expf(-acc));
    u[(size_t)m * DINNER + d] = v;
    u_bf[(size_t)m * DINNER + d] = __float2bfloat16(v);
}

// ------------------------- chunked selective scan ---------------------------
__global__ __launch_bounds__(256)
void scan_part1(const float* __restrict__ dt, const float* __restrict__ u,
                const float* __restrict__ bc, const float* __restrict__ A_log,
                float* __restrict__ s_end, float* __restrict__ dtsum)
{
    const int d = blockIdx.x * 256 + threadIdx.x;
    const int c = blockIdx.y;
    const int b = blockIdx.z;
    __shared__ float bcs[TCHUNK][32];
    {
        int f = threadIdx.x * 4;
        const float* src = bc + ((size_t)b * LSEQ + c * TCHUNK) * 32;
        *(float4*)&bcs[f >> 5][f & 31] = *(const float4*)&src[f];
    }
    float An[16];
    {
        float4 a0 = *(const float4*)&A_log[d * DSTATE + 0];
        float4 a1 = *(const float4*)&A_log[d * DSTATE + 4];
        float4 a2 = *(const float4*)&A_log[d * DSTATE + 8];
        float4 a3 = *(const float4*)&A_log[d * DSTATE + 12];
        An[0]=-__expf(a0.x); An[1]=-__expf(a0.y); An[2]=-__expf(a0.z); An[3]=-__expf(a0.w);
        An[4]=-__expf(a1.x); An[5]=-__expf(a1.y); An[6]=-__expf(a1.z); An[7]=-__expf(a1.w);
        An[8]=-__expf(a2.x); An[9]=-__expf(a2.y); An[10]=-__expf(a2.z); An[11]=-__expf(a2.w);
        An[12]=-__expf(a3.x); An[13]=-__expf(a3.y); An[14]=-__expf(a3.z); An[15]=-__expf(a3.w);
    }
    __syncthreads();
    const float* dtp = dt + ((size_t)b * LSEQ + c * TCHUNK) * DINNER + d;
    const float* up  = u  + ((size_t)b * LSEQ + c * TCHUNK) * DINNER + d;
    float s[16] = {};
    float sum = 0.f;
    for (int t = 0; t < TCHUNK; ++t) {
        float dtv = dtp[(size_t)t * DINNER];
        float uv  = up [(size_t)t * DINNER];
        sum += dtv;
        float du = dtv * uv;
        #pragma unroll
        for (int n = 0; n < 16; ++n) {
            float a = __expf(dtv * An[n]);
            s[n] = a * s[n] + du * bcs[t][n];
        }
    }
    float* se = s_end + ((size_t)(b * NCHUNK + c) * DINNER + d) * 16;
    #pragma unroll
    for (int q = 0; q < 4; ++q)
        *(float4*)&se[q * 4] = make_float4(s[q*4], s[q*4+1], s[q*4+2], s[q*4+3]);
    dtsum[(size_t)(b * NCHUNK + c) * DINNER + d] = sum;
}

// In-place combine: s_end[c] (chunk-local end state) -> state ENTERING chunk c.
__global__ __launch_bounds__(256)
void scan_combine(float* __restrict__ s_end, const float* __restrict__ dtsum,
                  const float* __restrict__ A_log)
{
    int idx = blockIdx.x * 256 + threadIdx.x;   // b*32768 + d*16 + n
    int n = idx & 15;
    int d = (idx >> 4) & (DINNER - 1);
    int b = idx >> 15;
    float An = -__expf(A_log[d * DSTATE + n]);
    float s = 0.f;
    for (int c = 0; c < NCHUNK; ++c) {
        size_t base = (size_t)(b * NCHUNK + c) * DINNER + d;
        float se = s_end[base * 16 + n];
        s_end[base * 16 + n] = s;
        float P = __expf(An * dtsum[base]);
        s = P * s + se;
    }
}

// Phase 3: local scan seeded with s_in; fuses y = sum_n s*C + D*u and the
// silu(z) gate; emits gated y as bf16.
__global__ __launch_bounds__(256)
void scan_part2(const float* __restrict__ dt, const float* __restrict__ u,
                const float* __restrict__ bc, const float* __restrict__ s_in,
                const float* __restrict__ A_log, const float* __restrict__ Dp,
                const float* __restrict__ xz, __hip_bfloat16* __restrict__ y_bf)
{
    const int d = blockIdx.x * 256 + threadIdx.x;
    const int c = blockIdx.y;
    const int b = blockIdx.z;
    __shared__ float bcs[TCHUNK][32];
    {
        int f = threadIdx.x * 4;
        const float* src = bc + ((size_t)b * LSEQ + c * TCHUNK) * 32;
        *(float4*)&bcs[f >> 5][f & 31] = *(const float4*)&src[f];
    }
    float An[16];
    {
        float4 a0 = *(const float4*)&A_log[d * DSTATE + 0];
        float4 a1 = *(const float4*)&A_log[d * DSTATE + 4];
        float4 a2 = *(const float4*)&A_log[d * DSTATE + 8];
        float4 a3 = *(const float4*)&A_log[d * DSTATE + 12];
        An[0]=-__expf(a0.x); An[1]=-__expf(a0.y); An[2]=-__expf(a0.z); An[3]=-__expf(a0.w);
        An[4]=-__expf(a1.x); An[5]=-__expf(a1.y); An[6]=-__expf(a1.z); An[7]=-__expf(a1.w);
        An[8]=-__expf(a2.x); An[9]=-__expf(a2.y); An[10]=-__expf(a2.z); An[11]=-__expf(a2.w);
        An[12]=-__expf(a3.x); An[13]=-__expf(a3.y); An[14]=-__expf(a3.z); An[15]=-__expf(a3.w);
    }
    float s[16];
    {
        const float* si = s_in + ((size_t)(b * NCHUNK + c) * DINNER + d) * 16;
        #pragma unroll
        for (int q = 0; q < 4; ++q) {
            float4 v = *(const float4*)&si[q * 4];
            s[q*4] = v.x; s[q*4+1] = v.y; s[q*4+2] = v.z; s[q*4+3] = v.w;
        }
    }
    const float Dd = Dp[d];
    __syncthreads();
    const float* dtp = dt + ((size_t)b * LSEQ + c * TCHUNK) * DINNER + d;
    const float* up  = u  + ((size_t)b * LSEQ + c * TCHUNK) * DINNER + d;
    const float* zp  = xz + ((size_t)b * LSEQ + c * TCHUNK) * 4096 + 2048 + d;
    __hip_bfloat16* yp = y_bf + ((size_t)b * LSEQ + c * TCHUNK) * DINNER + d;
    for (int t = 0; t < TCHUNK; ++t) {
        float dtv = dtp[(size_t)t * DINNER];
        float uv  = up [(size_t)t * DINNER];
        float du = dtv * uv;
        float y = Dd * uv;
        #pragma unroll
        for (int n = 0; n < 16; ++n) {
            float a = __expf(dtv * An[n]);
            s[n] = a * s[n] + du * bcs[t][n];
            y += s[n] * bcs[t][16 + n];
        }
        float zv = zp[(size_t)t * 4096];
        yp[(size_t)t * DINNER] = __float2bfloat16(y * (zv / (1.f + __expf(-zv))));
    }
}

// ---------------------------------------------------------------------------
extern "C" void kernel_launch(void* const* d_in, const int* in_sizes, int n_in,
                              void* d_out, int out_size, void* d_ws, size_t ws_size,
                              hipStream_t stream)
{
    const float* x      = (const float*)d_in[0];
    const float* W_in   = (const float*)d_in[1];
    const float* conv_w = (const float*)d_in[2];
    const float* conv_b = (const float*)d_in[3];
    const float* W_x    = (const float*)d_in[4];
    const float* W_dt   = (const float*)d_in[5];
    const float* b_dt   = (const float*)d_in[6];
    const float* A_log  = (const float*)d_in[7];
    const float* Dp     = (const float*)d_in[8];
    const float* W_out  = (const float*)d_in[9];
    float* out = (float*)d_out;

    const size_t MB = 1ull << 20;
    char* w8 = (char*)d_ws;
    float* xz    = (float*)(w8);              // 32MB  (2048 x 4096)
    float* u     = (float*)(w8 + 32*MB);      // 16MB
    float* dt    = (float*)(w8 + 48*MB);      // 16MB
    float* bc    = (float*)(w8 + 64*MB);      // 0.25MB
    float* sbuf  = (float*)(w8 + 65*MB);      // 8MB   s_end -> s_in (in place)
    float* dtsum = (float*)(w8 + 73*MB);      // 0.5MB
    __hip_bfloat16* u_bf   = (__hip_bfloat16*)(w8 + 74*MB);  // 8MB
    // region X (time-multiplexed):
    __hip_bfloat16* x_bf   = (__hip_bfloat16*)(w8 + 82*MB);  // 4MB   (GEMM1)
    __hip_bfloat16* Win_bf = (__hip_bfloat16*)(w8 + 86*MB);  // 8MB   (GEMM1)
    __hip_bfloat16* Wcat_bf= (__hip_bfloat16*)(w8 + 82*MB);  // 8.9MB (GEMM2)
    __hip_bfloat16* Wout_bf= (__hip_bfloat16*)(w8 + 91*MB);  // 4MB   (GEMM3)
    __hip_bfloat16* y_bf   = (__hip_bfloat16*)(w8 + 82*MB);  // 8MB   (GEMM3)
    // split-K partials for GEMM3: reuse xz region (dead after scan_part2)
    float* p0 = (float*)(w8);                 // 8MB
    float* p1 = (float*)(w8 + 8*MB);          // 8MB

    // 0. convert GEMM1 inputs
    cvt_bf16<<<(MROWS * DMODEL) / (256 * 8), 256, 0, stream>>>(x, x_bf);
    cvt_bf16<<<(4096 * DMODEL) / (256 * 8), 256, 0, stream>>>(W_in, Win_bf);
    // 1. xz = x @ W_in.T           (M=2048, N=4096, K=1024)
    gemm_bt<0, 128><<<dim3(16, 32, 1), 256, 0, stream>>>(
        x_bf, Win_bf, nullptr, xz, xz, 4096, nullptr, DMODEL, DMODEL);
    // 2. u = silu(causal_conv(xi) + conv_b)  (+ bf16 copy)
    conv_silu<<<(MROWS * DINNER) / 256, 256, 0, stream>>>(xz, conv_w, conv_b, u, u_bf);
    // 2b. build Wcat = [W_dt; W_x] bf16 (pad rows' columns never written), Wout
    cvt_bf16<<<(DINNER * DINNER) / (256 * 8), 256, 0, stream>>>(W_dt, Wcat_bf);
    cvt_bf16<<<(32 * DINNER) / (256 * 8), 256, 0, stream>>>(W_x, Wcat_bf + (size_t)DINNER * DINNER);
    cvt_bf16<<<(DMODEL * DINNER) / (256 * 8), 256, 0, stream>>>(W_out, Wout_bf);
    // 3. fused: dt = softplus(u@W_dt.T + b_dt), bc = u@W_x.T  (N=2176)
    gemm_bt<2, 64><<<dim3(16, NCAT / 64, 1), 256, 0, stream>>>(
        u_bf, Wcat_bf, b_dt, dt, dt, DINNER, bc, DINNER, DINNER);
    // 4. chunked scan (writes gated y as bf16)
    scan_part1<<<dim3(DINNER/256, NCHUNK, B_SZ), 256, 0, stream>>>(
        dt, u, bc, A_log, sbuf, dtsum);
    scan_combine<<<(B_SZ * DINNER * DSTATE) / 256, 256, 0, stream>>>(
        sbuf, dtsum, A_log);
    scan_part2<<<dim3(DINNER/256, NCHUNK, B_SZ), 256, 0, stream>>>(
        dt, u, bc, sbuf, A_log, Dp, xz, y_bf);
    // 5. out = y @ W_out.T  (M=2048, N=1024, K=2048), split-K=2 over xz region
    gemm_bt<0, 64><<<dim3(16, 16, 2), 256, 0, stream>>>(
        y_bf, Wout_bf, nullptr, p0, p1, DMODEL, nullptr, DINNER, DINNER / 2);
    add2<<<(MROWS * DMODEL) / (256 * 4), 256, 0, stream>>>(p0, p1, out);
}